// Round 6
// baseline (310.106 us; speedup 1.0000x reference)
//
#include <hip/hip_runtime.h>

#define B_ 16
#define N_ 1024
#define F_ 16
#define E_ 12
#define H_ 4

// One block per batch (16 blocks x 512 threads). Zero cross-block communication:
// all reductions are intra-block (quad shfl + LDS column-sum). No workspace use.

// shared-weight offsets
#define SW_WIN   0      // 192
#define SW_BIN   192    // 12
#define SW_WQKVS 204    // 432
#define SW_BQKVS 636    // 36
#define SW_WOS   672    // 144
#define SW_BOS   816    // 12
#define SW_WQKVC 828    // 432
#define SW_BQKVC 1260   // 36
#define SW_WOC   1296   // 144
#define SW_BOC   1440   // 12
#define SW_WOUT  1452   // 36
#define SW_BOUT  1488   // 3
#define SW_TOT   1491

// moment layout per head (39 used, stride 40):
// [0:3]=Sum k | [3:9]=Sum kk (00,11,22,01,02,12) | [9:12]=Sum v
// [12:21]=Sum k_i v_c | [21:39]=Sum kk_pair v_c

__device__ __forceinline__ void mom_compute(float k0, float k1, float k2,
                                            float v0, float v1, float v2, float* m) {
  m[0]=k0; m[1]=k1; m[2]=k2;
  float s00=k0*k0, s11=k1*k1, s22=k2*k2, s01=k0*k1, s02=k0*k2, s12=k1*k2;
  m[3]=s00; m[4]=s11; m[5]=s22; m[6]=s01; m[7]=s02; m[8]=s12;
  m[9]=v0; m[10]=v1; m[11]=v2;
  m[12]=k0*v0; m[13]=k0*v1; m[14]=k0*v2;
  m[15]=k1*v0; m[16]=k1*v1; m[17]=k1*v2;
  m[18]=k2*v0; m[19]=k2*v1; m[20]=k2*v2;
  m[21]=s00*v0; m[22]=s00*v1; m[23]=s00*v2;
  m[24]=s11*v0; m[25]=s11*v1; m[26]=s11*v2;
  m[27]=s22*v0; m[28]=s22*v1; m[29]=s22*v2;
  m[30]=s01*v0; m[31]=s01*v1; m[32]=s01*v2;
  m[33]=s02*v0; m[34]=s02*v1; m[35]=s02*v2;
  m[36]=s12*v0; m[37]=s12*v1; m[38]=s12*v2;
}

__device__ __forceinline__ void mom_accum(float k0, float k1, float k2,
                                          float v0, float v1, float v2, float* m) {
  m[0]+=k0; m[1]+=k1; m[2]+=k2;
  float s00=k0*k0, s11=k1*k1, s22=k2*k2, s01=k0*k1, s02=k0*k2, s12=k1*k2;
  m[3]+=s00; m[4]+=s11; m[5]+=s22; m[6]+=s01; m[7]+=s02; m[8]+=s12;
  m[9]+=v0; m[10]+=v1; m[11]+=v2;
  m[12]+=k0*v0; m[13]+=k0*v1; m[14]+=k0*v2;
  m[15]+=k1*v0; m[16]+=k1*v1; m[17]+=k1*v2;
  m[18]+=k2*v0; m[19]+=k2*v1; m[20]+=k2*v2;
  m[21]+=s00*v0; m[22]+=s00*v1; m[23]+=s00*v2;
  m[24]+=s11*v0; m[25]+=s11*v1; m[26]+=s11*v2;
  m[27]+=s22*v0; m[28]+=s22*v1; m[29]+=s22*v2;
  m[30]+=s01*v0; m[31]+=s01*v1; m[32]+=s01*v2;
  m[33]+=s02*v0; m[34]+=s02*v1; m[35]+=s02*v2;
  m[36]+=s12*v0; m[37]+=s12*v1; m[38]+=s12*v2;
}

// eval with pre-scaled moments (diag 2nd-order entries x0.5 applied at smu stage)
__device__ __forceinline__ void attn_eval(const float* __restrict__ mu,
                                          float p0, float p1, float p2, float* out) {
  float pp0=p0*p0, pp1=p1*p1, pp2=p2*p2;
  float q01=p0*p1, q02=p0*p2, q12=p1*p2;
  float den = (float)N_;
  den = fmaf(p0, mu[0], den); den = fmaf(p1, mu[1], den); den = fmaf(p2, mu[2], den);
  den = fmaf(pp0, mu[3], den); den = fmaf(pp1, mu[4], den); den = fmaf(pp2, mu[5], den);
  den = fmaf(q01, mu[6], den); den = fmaf(q02, mu[7], den); den = fmaf(q12, mu[8], den);
  float inv = 1.0f / den;
#pragma unroll
  for (int c = 0; c < 3; c++) {
    float num = mu[9+c];
    num = fmaf(p0, mu[12+c], num); num = fmaf(p1, mu[15+c], num); num = fmaf(p2, mu[18+c], num);
    num = fmaf(pp0, mu[21+c], num); num = fmaf(pp1, mu[24+c], num); num = fmaf(pp2, mu[27+c], num);
    num = fmaf(q01, mu[30+c], num); num = fmaf(q02, mu[33+c], num); num = fmaf(q12, mu[36+c], num);
    out[c] = num * inv;
  }
}

__device__ __forceinline__ float mom_scale(int j) {
  return ((j >= 3 && j < 6) || (j >= 21 && j < 30)) ? 0.5f : 1.0f;
}

__global__ __launch_bounds__(512, 1)
void k_all(const float* __restrict__ xo, const float* __restrict__ yo,
           const float* __restrict__ W_in, const float* __restrict__ b_in,
           const float* __restrict__ Wqkv_s, const float* __restrict__ bqkv_s,
           const float* __restrict__ Wo_s, const float* __restrict__ bo_s,
           const float* __restrict__ Wqkv_c, const float* __restrict__ bqkv_c,
           const float* __restrict__ Wo_c, const float* __restrict__ bo_c,
           const float* __restrict__ W_out, const float* __restrict__ b_out,
           float* __restrict__ out) {
  __shared__ float sw[SW_TOT];
  __shared__ float red[128 * 180];  // [quad128][176 used, stride 180]
  __shared__ float rawRx[176], rawRy[176];
  __shared__ float smuX[160], smuY[160], smuC[160];
  __shared__ float dqX[12], dqY[12];
  __shared__ float sredK[8][15];
  __shared__ float sXf[12];         // X[9] | tt[3]

  int tid = threadIdx.x;
  int b = blockIdx.x;
  int qd = tid >> 2;
  bool rep = (tid & 3) == 0;
  const float SC = 0.57735026918962584f;   // 1/sqrt(3)
  const float invN = 1.0f / N_;
  const float Nf = (float)N_;

  // persistent per-thread state
  float qx0[12], qx1[12];     // raw self-q, x tokens
  float qy0[12], qy1[12];     // raw self-q, y tokens
  float qc0[12], qc1[12];     // cross-q, x tokens
  float xr0[3], xr1[3];       // x3 (raw in A, centered in C)

  // ---- weights -> LDS ----
  for (int i = tid; i < SW_TOT; i += 512) {
    float v;
    if (i < 192)       v = W_in[i];
    else if (i < 204)  v = b_in[i - 192];
    else if (i < 636)  v = Wqkv_s[i - 204];
    else if (i < 672)  v = bqkv_s[i - 636];
    else if (i < 816)  v = Wo_s[i - 672];
    else if (i < 828)  v = bo_s[i - 816];
    else if (i < 1260) v = Wqkv_c[i - 828];
    else if (i < 1296) v = bqkv_c[i - 1260];
    else if (i < 1440) v = Wo_c[i - 1296];
    else if (i < 1452) v = bo_c[i - 1440];
    else if (i < 1488) v = W_out[i - 1452];
    else               v = b_out[i - 1488];
    sw[i] = v;
  }

  // ---- load x tokens (2 per thread) ----
  float av[16], bv[16];
  {
    const float4* p0 = (const float4*)(xo + ((size_t)b * N_ + tid) * F_);
    const float4* p1 = (const float4*)(xo + ((size_t)b * N_ + tid + 512) * F_);
#pragma unroll
    for (int q = 0; q < 4; q++) {
      float4 v0 = p0[q], v1 = p1[q];
      av[4*q+0]=v0.x; av[4*q+1]=v0.y; av[4*q+2]=v0.z; av[4*q+3]=v0.w;
      bv[4*q+0]=v1.x; bv[4*q+1]=v1.y; bv[4*q+2]=v1.z; bv[4*q+3]=v1.w;
    }
  }
  xr0[0]=av[0]; xr0[1]=av[1]; xr0[2]=av[2];
  xr1[0]=bv[0]; xr1[1]=bv[1]; xr1[2]=bv[2];
  __syncthreads();          // sw ready

  // ================= A-x: raw proj + self QKV + raw moments =================
  {
    float xiA[E_], xiB[E_];
#pragma unroll
    for (int e = 0; e < E_; e++) {
      float sa = sw[SW_BIN + e], sb = sa;
#pragma unroll
      for (int f = 0; f < F_; f++) {
        sa = fmaf(av[f], sw[SW_WIN + e*F_ + f], sa);
        sb = fmaf(bv[f], sw[SW_WIN + e*F_ + f], sb);
      }
      xiA[e] = sa; xiB[e] = sb;
    }
#pragma unroll
    for (int h = 0; h < H_; h++) {
      float ra[9], rb[9];
#pragma unroll
      for (int d = 0; d < 9; d++) {
        int o = (d/3)*12 + h*3 + (d%3);
        float sa = sw[SW_BQKVS + o], sb = sa;
#pragma unroll
        for (int e = 0; e < E_; e++) {
          sa = fmaf(xiA[e], sw[SW_WQKVS + o*E_ + e], sa);
          sb = fmaf(xiB[e], sw[SW_WQKVS + o*E_ + e], sb);
        }
        ra[d] = sa; rb[d] = sb;
      }
#pragma unroll
      for (int d = 0; d < 3; d++) { qx0[h*3+d] = ra[d]; qx1[h*3+d] = rb[d]; }
      float m[40];
      mom_compute(ra[3], ra[4], ra[5], ra[6], ra[7], ra[8], m);
      mom_accum (rb[3], rb[4], rb[5], rb[6], rb[7], rb[8], m);
      m[39] = 0.f;
#pragma unroll
      for (int j = 0; j < 39; j++) {
        m[j] += __shfl_xor(m[j], 1);
        m[j] += __shfl_xor(m[j], 2);
      }
      if (rep) {
#pragma unroll
        for (int j4 = 0; j4 < 10; j4++)
          *(float4*)&red[qd*180 + h*40 + j4*4] =
            make_float4(m[j4*4], m[j4*4+1], m[j4*4+2], m[j4*4+3]);
      }
    }
    float s[F_];
#pragma unroll
    for (int f = 0; f < F_; f++) {
      float v = av[f] + bv[f];
      v += __shfl_xor(v, 1);
      v += __shfl_xor(v, 2);
      s[f] = v;
    }
    if (rep) {
#pragma unroll
      for (int j4 = 0; j4 < 4; j4++)
        *(float4*)&red[qd*180 + 160 + j4*4] =
          make_float4(s[j4*4], s[j4*4+1], s[j4*4+2], s[j4*4+3]);
    }
  }
  // issue y loads now (hide latency under colsum)
  {
    const float4* p0 = (const float4*)(yo + ((size_t)b * N_ + tid) * F_);
    const float4* p1 = (const float4*)(yo + ((size_t)b * N_ + tid + 512) * F_);
#pragma unroll
    for (int q = 0; q < 4; q++) {
      float4 v0 = p0[q], v1 = p1[q];
      av[4*q+0]=v0.x; av[4*q+1]=v0.y; av[4*q+2]=v0.z; av[4*q+3]=v0.w;
      bv[4*q+0]=v1.x; bv[4*q+1]=v1.y; bv[4*q+2]=v1.z; bv[4*q+3]=v1.w;
    }
  }
  __syncthreads();
  for (int col = tid; col < 176; col += 512) {
    float a = 0.f;
    for (int q = 0; q < 128; q++) a += red[q*180 + col];
    rawRx[col] = a;
  }
  __syncthreads();

  // ================= A-y =================
  {
    float xiA[E_], xiB[E_];
#pragma unroll
    for (int e = 0; e < E_; e++) {
      float sa = sw[SW_BIN + e], sb = sa;
#pragma unroll
      for (int f = 0; f < F_; f++) {
        sa = fmaf(av[f], sw[SW_WIN + e*F_ + f], sa);
        sb = fmaf(bv[f], sw[SW_WIN + e*F_ + f], sb);
      }
      xiA[e] = sa; xiB[e] = sb;
    }
#pragma unroll
    for (int h = 0; h < H_; h++) {
      float ra[9], rb[9];
#pragma unroll
      for (int d = 0; d < 9; d++) {
        int o = (d/3)*12 + h*3 + (d%3);
        float sa = sw[SW_BQKVS + o], sb = sa;
#pragma unroll
        for (int e = 0; e < E_; e++) {
          sa = fmaf(xiA[e], sw[SW_WQKVS + o*E_ + e], sa);
          sb = fmaf(xiB[e], sw[SW_WQKVS + o*E_ + e], sb);
        }
        ra[d] = sa; rb[d] = sb;
      }
#pragma unroll
      for (int d = 0; d < 3; d++) { qy0[h*3+d] = ra[d]; qy1[h*3+d] = rb[d]; }
      float m[40];
      mom_compute(ra[3], ra[4], ra[5], ra[6], ra[7], ra[8], m);
      mom_accum (rb[3], rb[4], rb[5], rb[6], rb[7], rb[8], m);
      m[39] = 0.f;
#pragma unroll
      for (int j = 0; j < 39; j++) {
        m[j] += __shfl_xor(m[j], 1);
        m[j] += __shfl_xor(m[j], 2);
      }
      if (rep) {
#pragma unroll
        for (int j4 = 0; j4 < 10; j4++)
          *(float4*)&red[qd*180 + h*40 + j4*4] =
            make_float4(m[j4*4], m[j4*4+1], m[j4*4+2], m[j4*4+3]);
      }
    }
    float s[F_];
#pragma unroll
    for (int f = 0; f < F_; f++) {
      float v = av[f] + bv[f];
      v += __shfl_xor(v, 1);
      v += __shfl_xor(v, 2);
      s[f] = v;
    }
    if (rep) {
#pragma unroll
      for (int j4 = 0; j4 < 4; j4++)
        *(float4*)&red[qd*180 + 160 + j4*4] =
          make_float4(s[j4*4], s[j4*4+1], s[j4*4+2], s[j4*4+3]);
    }
  }
  __syncthreads();
  for (int col = tid; col < 176; col += 512) {
    float a = 0.f;
    for (int q = 0; q < 128; q++) a += red[q*180 + col];
    rawRy[col] = a;
  }
  __syncthreads();

  // ---- shifted-moment corrections: tid 0..7 = (side, head) ----
  if (tid < 8) {
    int side = tid >> 2, h = tid & 3;
    const float* R0 = side ? rawRy : rawRx;
    float* SM = side ? smuY : smuX;
    float* DQ = side ? dqY : dqX;
    float del[E_];
#pragma unroll
    for (int e = 0; e < E_; e++) {
      float s = 0.f;
#pragma unroll
      for (int f = 0; f < F_; f++) s = fmaf(R0[160+f], sw[SW_WIN + e*F_ + f], s);
      del[e] = s * invN;
    }
    float A[3], G[3];
#pragma unroll
    for (int d = 0; d < 3; d++) {
      float sq=0.f, sk=0.f, sv=0.f;
#pragma unroll
      for (int e = 0; e < E_; e++) {
        sq = fmaf(del[e], sw[SW_WQKVS + (h*3+d)*E_ + e], sq);
        sk = fmaf(del[e], sw[SW_WQKVS + (12 + h*3+d)*E_ + e], sk);
        sv = fmaf(del[e], sw[SW_WQKVS + (24 + h*3+d)*E_ + e], sv);
      }
      DQ[h*3+d] = sq; A[d] = sk; G[d] = sv;
    }
    const float* R = &R0[h*40];
    float S[39];
#pragma unroll
    for (int i = 0; i < 3; i++) S[i] = R[i] - Nf*A[i];
    const int PI[6] = {0,1,2,0,0,1}, PJ[6] = {0,1,2,1,2,2};
#pragma unroll
    for (int p = 0; p < 6; p++) {
      int i = PI[p], j = PJ[p];
      S[3+p] = R[3+p] - A[i]*R[j] - A[j]*R[i] + Nf*A[i]*A[j];
    }
#pragma unroll
    for (int cc = 0; cc < 3; cc++) S[9+cc] = R[9+cc] - Nf*G[cc];
#pragma unroll
    for (int i = 0; i < 3; i++)
#pragma unroll
      for (int cc = 0; cc < 3; cc++)
        S[12+i*3+cc] = R[12+i*3+cc] - A[i]*R[9+cc] - G[cc]*R[i] + Nf*A[i]*G[cc];
#pragma unroll
    for (int p = 0; p < 6; p++) {
      int i = PI[p], j = PJ[p];
#pragma unroll
      for (int cc = 0; cc < 3; cc++) {
        S[21+p*3+cc] = R[21+p*3+cc]
                     - A[i]*R[12+j*3+cc] - A[j]*R[12+i*3+cc]
                     - G[cc]*R[3+p]
                     + A[i]*A[j]*R[9+cc]
                     + A[i]*G[cc]*R[j] + A[j]*G[cc]*R[i]
                     - Nf*A[i]*A[j]*G[cc];
      }
    }
#pragma unroll
    for (int j = 0; j < 39; j++) SM[h*40+j] = S[j] * mom_scale(j);
    SM[h*40+39] = 0.f;
  }
  __syncthreads();

  // ================= B-x: self-attn + cross-q =================
  {
    float attn[E_], i2[E_];
#pragma unroll
    for (int h = 0; h < H_; h++)
      attn_eval(&smuX[h*40], (qx0[h*3+0]-dqX[h*3+0])*SC, (qx0[h*3+1]-dqX[h*3+1])*SC,
                (qx0[h*3+2]-dqX[h*3+2])*SC, &attn[h*3]);
#pragma unroll
    for (int e = 0; e < E_; e++) {
      float s = sw[SW_BOS + e];
#pragma unroll
      for (int j = 0; j < E_; j++) s = fmaf(attn[j], sw[SW_WOS + e*E_ + j], s);
      i2[e] = s;
    }
#pragma unroll
    for (int o = 0; o < 12; o++) {
      float s = sw[SW_BQKVC + o];
#pragma unroll
      for (int e = 0; e < E_; e++) s = fmaf(i2[e], sw[SW_WQKVC + o*E_ + e], s);
      qc0[o] = s;
    }
#pragma unroll
    for (int h = 0; h < H_; h++)
      attn_eval(&smuX[h*40], (qx1[h*3+0]-dqX[h*3+0])*SC, (qx1[h*3+1]-dqX[h*3+1])*SC,
                (qx1[h*3+2]-dqX[h*3+2])*SC, &attn[h*3]);
#pragma unroll
    for (int e = 0; e < E_; e++) {
      float s = sw[SW_BOS + e];
#pragma unroll
      for (int j = 0; j < E_; j++) s = fmaf(attn[j], sw[SW_WOS + e*E_ + j], s);
      i2[e] = s;
    }
#pragma unroll
    for (int o = 0; o < 12; o++) {
      float s = sw[SW_BQKVC + o];
#pragma unroll
      for (int e = 0; e < E_; e++) s = fmaf(i2[e], sw[SW_WQKVC + o*E_ + e], s);
      qc1[o] = s;
    }
  }
  // ================= B-y: self-attn + cross k/v moments =================
  {
    float attn[E_], i2a[E_], i2b[E_];
#pragma unroll
    for (int h = 0; h < H_; h++)
      attn_eval(&smuY[h*40], (qy0[h*3+0]-dqY[h*3+0])*SC, (qy0[h*3+1]-dqY[h*3+1])*SC,
                (qy0[h*3+2]-dqY[h*3+2])*SC, &attn[h*3]);
#pragma unroll
    for (int e = 0; e < E_; e++) {
      float s = sw[SW_BOS + e];
#pragma unroll
      for (int j = 0; j < E_; j++) s = fmaf(attn[j], sw[SW_WOS + e*E_ + j], s);
      i2a[e] = s;
    }
#pragma unroll
    for (int h = 0; h < H_; h++)
      attn_eval(&smuY[h*40], (qy1[h*3+0]-dqY[h*3+0])*SC, (qy1[h*3+1]-dqY[h*3+1])*SC,
                (qy1[h*3+2]-dqY[h*3+2])*SC, &attn[h*3]);
#pragma unroll
    for (int e = 0; e < E_; e++) {
      float s = sw[SW_BOS + e];
#pragma unroll
      for (int j = 0; j < E_; j++) s = fmaf(attn[j], sw[SW_WOS + e*E_ + j], s);
      i2b[e] = s;
    }
#pragma unroll
    for (int h = 0; h < H_; h++) {
      float ka[6], kb[6];
#pragma unroll
      for (int d = 0; d < 6; d++) {
        int o = 12 + (d/3)*12 + h*3 + (d%3);
        float sa = sw[SW_BQKVC + o], sb = sa;
#pragma unroll
        for (int e = 0; e < E_; e++) {
          sa = fmaf(i2a[e], sw[SW_WQKVC + o*E_ + e], sa);
          sb = fmaf(i2b[e], sw[SW_WQKVC + o*E_ + e], sb);
        }
        ka[d] = sa; kb[d] = sb;
      }
      float m[40];
      mom_compute(ka[0], ka[1], ka[2], ka[3], ka[4], ka[5], m);
      mom_accum (kb[0], kb[1], kb[2], kb[3], kb[4], kb[5], m);
      m[39] = 0.f;
#pragma unroll
      for (int j = 0; j < 39; j++) {
        m[j] += __shfl_xor(m[j], 1);
        m[j] += __shfl_xor(m[j], 2);
      }
      if (rep) {
#pragma unroll
        for (int j4 = 0; j4 < 10; j4++)
          *(float4*)&red[qd*180 + h*40 + j4*4] =
            make_float4(m[j4*4], m[j4*4+1], m[j4*4+2], m[j4*4+3]);
      }
    }
  }
  __syncthreads();
  for (int col = tid; col < 160; col += 512) {
    float a = 0.f;
    for (int q = 0; q < 128; q++) a += red[q*180 + col];
    int j = col - (col/40)*40;
    smuC[col] = a * mom_scale(j);
  }
  __syncthreads();

  // ================= C: cross-attn + Kabsch stats (x tokens) =================
  {
    float st[15];
#pragma unroll
    for (int i = 0; i < 15; i++) st[i] = 0.f;
    float attn[E_], c12[E_], co[3];
    // token 0
#pragma unroll
    for (int h = 0; h < H_; h++)
      attn_eval(&smuC[h*40], qc0[h*3+0]*SC, qc0[h*3+1]*SC, qc0[h*3+2]*SC, &attn[h*3]);
#pragma unroll
    for (int e = 0; e < E_; e++) {
      float s = sw[SW_BOC + e];
#pragma unroll
      for (int j = 0; j < E_; j++) s = fmaf(attn[j], sw[SW_WOC + e*E_ + j], s);
      c12[e] = s;
    }
#pragma unroll
    for (int k = 0; k < 3; k++) {
      float s = sw[SW_BOUT + k];
#pragma unroll
      for (int e = 0; e < E_; e++) s = fmaf(c12[e], sw[SW_WOUT + k*E_ + e], s);
      co[k] = s;
    }
    xr0[0] -= rawRx[160]*invN; xr0[1] -= rawRx[161]*invN; xr0[2] -= rawRx[162]*invN;
    {
      float A0 = co[0]+xr0[0], A1 = co[1]+xr0[1], A2 = co[2]+xr0[2];
      st[0]+=co[0]; st[1]+=co[1]; st[2]+=co[2];
      st[3]+=xr0[0]; st[4]+=xr0[1]; st[5]+=xr0[2];
      st[6]=fmaf(xr0[0],A0,st[6]);  st[7]=fmaf(xr0[0],A1,st[7]);  st[8]=fmaf(xr0[0],A2,st[8]);
      st[9]=fmaf(xr0[1],A0,st[9]);  st[10]=fmaf(xr0[1],A1,st[10]); st[11]=fmaf(xr0[1],A2,st[11]);
      st[12]=fmaf(xr0[2],A0,st[12]); st[13]=fmaf(xr0[2],A1,st[13]); st[14]=fmaf(xr0[2],A2,st[14]);
    }
    // token 1
#pragma unroll
    for (int h = 0; h < H_; h++)
      attn_eval(&smuC[h*40], qc1[h*3+0]*SC, qc1[h*3+1]*SC, qc1[h*3+2]*SC, &attn[h*3]);
#pragma unroll
    for (int e = 0; e < E_; e++) {
      float s = sw[SW_BOC + e];
#pragma unroll
      for (int j = 0; j < E_; j++) s = fmaf(attn[j], sw[SW_WOC + e*E_ + j], s);
      c12[e] = s;
    }
#pragma unroll
    for (int k = 0; k < 3; k++) {
      float s = sw[SW_BOUT + k];
#pragma unroll
      for (int e = 0; e < E_; e++) s = fmaf(c12[e], sw[SW_WOUT + k*E_ + e], s);
      co[k] = s;
    }
    xr1[0] -= rawRx[160]*invN; xr1[1] -= rawRx[161]*invN; xr1[2] -= rawRx[162]*invN;
    {
      float A0 = co[0]+xr1[0], A1 = co[1]+xr1[1], A2 = co[2]+xr1[2];
      st[0]+=co[0]; st[1]+=co[1]; st[2]+=co[2];
      st[3]+=xr1[0]; st[4]+=xr1[1]; st[5]+=xr1[2];
      st[6]=fmaf(xr1[0],A0,st[6]);  st[7]=fmaf(xr1[0],A1,st[7]);  st[8]=fmaf(xr1[0],A2,st[8]);
      st[9]=fmaf(xr1[1],A0,st[9]);  st[10]=fmaf(xr1[1],A1,st[10]); st[11]=fmaf(xr1[1],A2,st[11]);
      st[12]=fmaf(xr1[2],A0,st[12]); st[13]=fmaf(xr1[2],A1,st[13]); st[14]=fmaf(xr1[2],A2,st[14]);
    }
#pragma unroll
    for (int i = 0; i < 15; i++) {
      st[i] += __shfl_down(st[i], 32); st[i] += __shfl_down(st[i], 16);
      st[i] += __shfl_down(st[i], 8);  st[i] += __shfl_down(st[i], 4);
      st[i] += __shfl_down(st[i], 2);  st[i] += __shfl_down(st[i], 1);
    }
    if ((tid & 63) == 0) {
      int wv = tid >> 6;
#pragma unroll
      for (int i = 0; i < 15; i++) sredK[wv][i] = st[i];
    }
  }
  __syncthreads();

  // ================= D: polar (wave 0) + transform (all) =================
  if (tid < 64) {
    float s[15];
#pragma unroll
    for (int i = 0; i < 15; i++) {
      float a = 0.f;
#pragma unroll
      for (int w = 0; w < 8; w++) a += sredK[w][i];
      s[i] = a;
    }
    float cB[3] = { s[3]*invN, s[4]*invN, s[5]*invN };
    float cA[3] = { (s[0]+s[3])*invN, (s[1]+s[4])*invN, (s[2]+s[5])*invN };
    float X[9];
#pragma unroll
    for (int i = 0; i < 3; i++)
#pragma unroll
      for (int j = 0; j < 3; j++)
        X[i*3+j] = s[6 + i*3 + j] - Nf * cB[i] * cA[j];
    float fn = 0.f;
#pragma unroll
    for (int i = 0; i < 9; i++) fn += X[i]*X[i];
    float scl = rsqrtf(fn);
#pragma unroll
    for (int i = 0; i < 9; i++) X[i] *= scl;
    for (int it = 0; it < 24; it++) {
      float c00 =  X[4]*X[8]-X[5]*X[7];
      float c01 = -(X[3]*X[8]-X[5]*X[6]);
      float c02 =  X[3]*X[7]-X[4]*X[6];
      float c10 = -(X[1]*X[8]-X[2]*X[7]);
      float c11 =  X[0]*X[8]-X[2]*X[6];
      float c12_= -(X[0]*X[7]-X[1]*X[6]);
      float c20 =  X[1]*X[5]-X[2]*X[4];
      float c21 = -(X[0]*X[5]-X[2]*X[3]);
      float c22 =  X[0]*X[4]-X[1]*X[3];
      float det = X[0]*c00 + X[1]*c01 + X[2]*c02;
      float id = 0.5f / det;
      X[0]=0.5f*X[0]+c00*id; X[1]=0.5f*X[1]+c01*id; X[2]=0.5f*X[2]+c02*id;
      X[3]=0.5f*X[3]+c10*id; X[4]=0.5f*X[4]+c11*id; X[5]=0.5f*X[5]+c12_*id;
      X[6]=0.5f*X[6]+c20*id; X[7]=0.5f*X[7]+c21*id; X[8]=0.5f*X[8]+c22*id;
    }
    if (tid == 0) {
#pragma unroll
      for (int i = 0; i < 9; i++) sXf[i] = X[i];
#pragma unroll
      for (int k = 0; k < 3; k++)
        sXf[9+k] = cA[k] - (cB[0]*X[k] + cB[1]*X[3+k] + cB[2]*X[6+k]) + rawRy[160+k]*invN;
    }
  }
  __syncthreads();
  {
    float X0=sXf[0], X1=sXf[1], X2=sXf[2], X3=sXf[3], X4=sXf[4], X5=sXf[5],
          X6=sXf[6], X7=sXf[7], X8=sXf[8], t0=sXf[9], t1=sXf[10], t2=sXf[11];
    size_t ta = (size_t)b * N_ + tid;
    size_t tb = ta + 512;
    out[ta*3+0] = fmaf(xr0[0], X0, fmaf(xr0[1], X3, fmaf(xr0[2], X6, t0)));
    out[ta*3+1] = fmaf(xr0[0], X1, fmaf(xr0[1], X4, fmaf(xr0[2], X7, t1)));
    out[ta*3+2] = fmaf(xr0[0], X2, fmaf(xr0[1], X5, fmaf(xr0[2], X8, t2)));
    out[tb*3+0] = fmaf(xr1[0], X0, fmaf(xr1[1], X3, fmaf(xr1[2], X6, t0)));
    out[tb*3+1] = fmaf(xr1[0], X1, fmaf(xr1[1], X4, fmaf(xr1[2], X7, t1)));
    out[tb*3+2] = fmaf(xr1[0], X2, fmaf(xr1[1], X5, fmaf(xr1[2], X8, t2)));
  }
}

extern "C" void kernel_launch(void* const* d_in, const int* in_sizes, int n_in,
                              void* d_out, int out_size, void* d_ws, size_t ws_size,
                              hipStream_t stream) {
  const float* x_orig = (const float*)d_in[0];
  const float* y_orig = (const float*)d_in[1];
  const float* W_in   = (const float*)d_in[2];
  const float* b_in   = (const float*)d_in[3];
  const float* Wqkv_s = (const float*)d_in[4];
  const float* bqkv_s = (const float*)d_in[5];
  const float* Wo_s   = (const float*)d_in[6];
  const float* bo_s   = (const float*)d_in[7];
  const float* Wqkv_c = (const float*)d_in[8];
  const float* bqkv_c = (const float*)d_in[9];
  const float* Wo_c   = (const float*)d_in[10];
  const float* bo_c   = (const float*)d_in[11];
  const float* W_out  = (const float*)d_in[12];
  const float* b_out  = (const float*)d_in[13];

  k_all<<<B_, 512, 0, stream>>>(x_orig, y_orig, W_in, b_in, Wqkv_s, bqkv_s,
                                Wo_s, bo_s, Wqkv_c, bqkv_c, Wo_c, bo_c,
                                W_out, b_out, (float*)d_out);
}

// Round 7
// 164.586 us; speedup vs baseline: 1.8842x; 1.8842x over previous
//
#include <hip/hip_runtime.h>

#define B_ 16
#define N_ 1024
#define F_ 16
#define E_ 12
#define H_ 4

// 32 blocks x 256 threads: block (side,b) owns all 1024 tokens of that side/batch.
// Single cross-block hop: y-block publishes cross k/v moment sums + y-mean -> x-block.
// ws: psC[16][160] | ymean[16][3] | flags[16] u64
#define OFF_PC 0
#define OFF_YM 2560
#define OFF_FLAG 2608   // float offset; byte offset 10432 (8-aligned)
#define TAG_C 0x51A7E0C5ull

// shared-weight offsets
#define SW_WIN   0      // 192
#define SW_BIN   192    // 12
#define SW_WQKVS 204    // 432
#define SW_BQKVS 636    // 36
#define SW_WOS   672    // 144
#define SW_BOS   816    // 12
#define SW_WQKVC 828    // 432
#define SW_BQKVC 1260   // 36
#define SW_WOC   1296   // 144
#define SW_BOC   1440   // 12
#define SW_WOUT  1452   // 36
#define SW_BOUT  1488   // 3
#define SW_TOT   1491

// moment layout per head (39 used, stride 40):
// [0:3]=Sum k | [3:9]=Sum kk (00,11,22,01,02,12) | [9:12]=Sum v
// [12:21]=Sum k_i v_c | [21:39]=Sum kk_pair v_c

__device__ __forceinline__ void data_store(float* p, float v) {
  __hip_atomic_store((unsigned*)p, __float_as_uint(v),
                     __ATOMIC_RELAXED, __HIP_MEMORY_SCOPE_AGENT);
}
__device__ __forceinline__ float data_load(const float* p) {
  unsigned u = __hip_atomic_load((const unsigned*)p,
                                 __ATOMIC_RELAXED, __HIP_MEMORY_SCOPE_AGENT);
  return __uint_as_float(u);
}
__device__ __forceinline__ void flag_set(unsigned long long* f, unsigned long long tag) {
  __hip_atomic_store(f, tag, __ATOMIC_RELAXED, __HIP_MEMORY_SCOPE_AGENT);
}
__device__ __forceinline__ void flag_wait(unsigned long long* f, unsigned long long tag) {
  while (__hip_atomic_load(f, __ATOMIC_RELAXED, __HIP_MEMORY_SCOPE_AGENT) != tag)
    __builtin_amdgcn_s_sleep(2);
  asm volatile("" ::: "memory");
}

__device__ __forceinline__ void mom_compute(float k0, float k1, float k2,
                                            float v0, float v1, float v2, float* m) {
  m[0]=k0; m[1]=k1; m[2]=k2;
  float s00=k0*k0, s11=k1*k1, s22=k2*k2, s01=k0*k1, s02=k0*k2, s12=k1*k2;
  m[3]=s00; m[4]=s11; m[5]=s22; m[6]=s01; m[7]=s02; m[8]=s12;
  m[9]=v0; m[10]=v1; m[11]=v2;
  m[12]=k0*v0; m[13]=k0*v1; m[14]=k0*v2;
  m[15]=k1*v0; m[16]=k1*v1; m[17]=k1*v2;
  m[18]=k2*v0; m[19]=k2*v1; m[20]=k2*v2;
  m[21]=s00*v0; m[22]=s00*v1; m[23]=s00*v2;
  m[24]=s11*v0; m[25]=s11*v1; m[26]=s11*v2;
  m[27]=s22*v0; m[28]=s22*v1; m[29]=s22*v2;
  m[30]=s01*v0; m[31]=s01*v1; m[32]=s01*v2;
  m[33]=s02*v0; m[34]=s02*v1; m[35]=s02*v2;
  m[36]=s12*v0; m[37]=s12*v1; m[38]=s12*v2;
}

__device__ __forceinline__ void mom_accum(float k0, float k1, float k2,
                                          float v0, float v1, float v2, float* m) {
  m[0]+=k0; m[1]+=k1; m[2]+=k2;
  float s00=k0*k0, s11=k1*k1, s22=k2*k2, s01=k0*k1, s02=k0*k2, s12=k1*k2;
  m[3]+=s00; m[4]+=s11; m[5]+=s22; m[6]+=s01; m[7]+=s02; m[8]+=s12;
  m[9]+=v0; m[10]+=v1; m[11]+=v2;
  m[12]+=k0*v0; m[13]+=k0*v1; m[14]+=k0*v2;
  m[15]+=k1*v0; m[16]+=k1*v1; m[17]+=k1*v2;
  m[18]+=k2*v0; m[19]+=k2*v1; m[20]+=k2*v2;
  m[21]+=s00*v0; m[22]+=s00*v1; m[23]+=s00*v2;
  m[24]+=s11*v0; m[25]+=s11*v1; m[26]+=s11*v2;
  m[27]+=s22*v0; m[28]+=s22*v1; m[29]+=s22*v2;
  m[30]+=s01*v0; m[31]+=s01*v1; m[32]+=s01*v2;
  m[33]+=s02*v0; m[34]+=s02*v1; m[35]+=s02*v2;
  m[36]+=s12*v0; m[37]+=s12*v1; m[38]+=s12*v2;
}

// eval with pre-scaled moments (diag 2nd-order entries x0.5 applied at smu stage)
__device__ __forceinline__ void attn_eval(const float* __restrict__ mu,
                                          float p0, float p1, float p2, float* out) {
  float pp0=p0*p0, pp1=p1*p1, pp2=p2*p2;
  float q01=p0*p1, q02=p0*p2, q12=p1*p2;
  float den = (float)N_;
  den = fmaf(p0, mu[0], den); den = fmaf(p1, mu[1], den); den = fmaf(p2, mu[2], den);
  den = fmaf(pp0, mu[3], den); den = fmaf(pp1, mu[4], den); den = fmaf(pp2, mu[5], den);
  den = fmaf(q01, mu[6], den); den = fmaf(q02, mu[7], den); den = fmaf(q12, mu[8], den);
  float inv = 1.0f / den;
#pragma unroll
  for (int c = 0; c < 3; c++) {
    float num = mu[9+c];
    num = fmaf(p0, mu[12+c], num); num = fmaf(p1, mu[15+c], num); num = fmaf(p2, mu[18+c], num);
    num = fmaf(pp0, mu[21+c], num); num = fmaf(pp1, mu[24+c], num); num = fmaf(pp2, mu[27+c], num);
    num = fmaf(q01, mu[30+c], num); num = fmaf(q02, mu[33+c], num); num = fmaf(q12, mu[36+c], num);
    out[c] = num * inv;
  }
}

__device__ __forceinline__ float mom_scale(int j) {
  return ((j >= 3 && j < 6) || (j >= 21 && j < 30)) ? 0.5f : 1.0f;
}

__global__ __launch_bounds__(256, 1)
void k_all(const float* __restrict__ xo, const float* __restrict__ yo,
           const float* __restrict__ W_in, const float* __restrict__ b_in,
           const float* __restrict__ Wqkv_s, const float* __restrict__ bqkv_s,
           const float* __restrict__ Wo_s, const float* __restrict__ bo_s,
           const float* __restrict__ Wqkv_c, const float* __restrict__ bqkv_c,
           const float* __restrict__ Wo_c, const float* __restrict__ bo_c,
           const float* __restrict__ W_out, const float* __restrict__ b_out,
           float* __restrict__ ws, float* __restrict__ out) {
  __shared__ float sw[SW_TOT];
  __shared__ float red[64 * 180];   // [quad64][176 used, stride 180]
  __shared__ float rawR[176];       // own-side raw sums
  __shared__ float smu[160];        // own-side corrected self moments
  __shared__ float dq[12];
  __shared__ float smuC[160];       // cross moments (x blocks)
  __shared__ float myY[3];
  __shared__ float sredK[4][15];
  __shared__ float sXf[12];

  float* psC = ws + OFF_PC;
  float* pYM = ws + OFF_YM;
  unsigned long long* flags = (unsigned long long*)(ws + OFF_FLAG);

  int tid = threadIdx.x;
  int blk = blockIdx.x;
  int side = blk >> 4;              // x blocks 0..15, y blocks 16..31 (same XCD as pair)
  int b = blk & 15;
  int qd = tid >> 2;
  bool rep = (tid & 3) == 0;
  const float SC = 0.57735026918962584f;   // 1/sqrt(3)
  const float invN = 1.0f / N_;
  const float Nf = (float)N_;

  float qq[4][12];                  // raw self-q, 4 tokens
  float qc[4][12];                  // cross-q (x side)
  float xr[4][3];                   // x3 (x side)

  // ---- weights -> LDS ----
  for (int i = tid; i < SW_TOT; i += 256) {
    float v;
    if (i < 192)       v = W_in[i];
    else if (i < 204)  v = b_in[i - 192];
    else if (i < 636)  v = Wqkv_s[i - 204];
    else if (i < 672)  v = bqkv_s[i - 636];
    else if (i < 816)  v = Wo_s[i - 672];
    else if (i < 828)  v = bo_s[i - 816];
    else if (i < 1260) v = Wqkv_c[i - 828];
    else if (i < 1296) v = bqkv_c[i - 1260];
    else if (i < 1440) v = Wo_c[i - 1296];
    else if (i < 1452) v = bo_c[i - 1440];
    else if (i < 1488) v = W_out[i - 1452];
    else               v = b_out[i - 1488];
    sw[i] = v;
  }
  const float* src = side ? yo : xo;
  __syncthreads();

  // ================= Phase A: 2 passes x 2 tokens; raw proj + QKV + moments =================
#pragma unroll
  for (int p = 0; p < 2; p++) {
    float av[16], bv[16];
    {
      const float4* p0 = (const float4*)(src + ((size_t)b * N_ + p*512 + tid) * F_);
      const float4* p1 = (const float4*)(src + ((size_t)b * N_ + p*512 + 256 + tid) * F_);
#pragma unroll
      for (int q = 0; q < 4; q++) {
        float4 v0 = p0[q], v1 = p1[q];
        av[4*q+0]=v0.x; av[4*q+1]=v0.y; av[4*q+2]=v0.z; av[4*q+3]=v0.w;
        bv[4*q+0]=v1.x; bv[4*q+1]=v1.y; bv[4*q+2]=v1.z; bv[4*q+3]=v1.w;
      }
    }
    if (!side) {
      xr[p*2][0]=av[0]; xr[p*2][1]=av[1]; xr[p*2][2]=av[2];
      xr[p*2+1][0]=bv[0]; xr[p*2+1][1]=bv[1]; xr[p*2+1][2]=bv[2];
    }
    float xiA[E_], xiB[E_];
#pragma unroll
    for (int e = 0; e < E_; e++) {
      float sa = sw[SW_BIN + e], sb = sa;
#pragma unroll
      for (int f = 0; f < F_; f++) {
        sa = fmaf(av[f], sw[SW_WIN + e*F_ + f], sa);
        sb = fmaf(bv[f], sw[SW_WIN + e*F_ + f], sb);
      }
      xiA[e] = sa; xiB[e] = sb;
    }
#pragma unroll
    for (int h = 0; h < H_; h++) {
      float ra[9], rb[9];
#pragma unroll
      for (int d = 0; d < 9; d++) {
        int o = (d/3)*12 + h*3 + (d%3);
        float sa = sw[SW_BQKVS + o], sb = sa;
#pragma unroll
        for (int e = 0; e < E_; e++) {
          sa = fmaf(xiA[e], sw[SW_WQKVS + o*E_ + e], sa);
          sb = fmaf(xiB[e], sw[SW_WQKVS + o*E_ + e], sb);
        }
        ra[d] = sa; rb[d] = sb;
      }
#pragma unroll
      for (int d = 0; d < 3; d++) { qq[p*2][h*3+d] = ra[d]; qq[p*2+1][h*3+d] = rb[d]; }
      float m[40];
      mom_compute(ra[3], ra[4], ra[5], ra[6], ra[7], ra[8], m);
      mom_accum (rb[3], rb[4], rb[5], rb[6], rb[7], rb[8], m);
      m[39] = 0.f;
#pragma unroll
      for (int j = 0; j < 39; j++) {
        m[j] += __shfl_xor(m[j], 1);
        m[j] += __shfl_xor(m[j], 2);
      }
      if (rep) {
        if (p == 0) {
#pragma unroll
          for (int j4 = 0; j4 < 10; j4++)
            *(float4*)&red[qd*180 + h*40 + j4*4] =
              make_float4(m[j4*4], m[j4*4+1], m[j4*4+2], m[j4*4+3]);
        } else {
#pragma unroll
          for (int j = 0; j < 40; j++) red[qd*180 + h*40 + j] += m[j];
        }
      }
    }
    {
      float s[F_];
#pragma unroll
      for (int f = 0; f < F_; f++) {
        float v = av[f] + bv[f];
        v += __shfl_xor(v, 1);
        v += __shfl_xor(v, 2);
        s[f] = v;
      }
      if (rep) {
        if (p == 0) {
#pragma unroll
          for (int j4 = 0; j4 < 4; j4++)
            *(float4*)&red[qd*180 + 160 + j4*4] =
              make_float4(s[j4*4], s[j4*4+1], s[j4*4+2], s[j4*4+3]);
        } else {
#pragma unroll
          for (int f = 0; f < F_; f++) red[qd*180 + 160 + f] += s[f];
        }
      }
    }
  }
  __syncthreads();
  for (int col = tid; col < 176; col += 256) {
    float a = 0.f;
    for (int q = 0; q < 64; q++) a += red[q*180 + col];
    rawR[col] = a;
  }
  __syncthreads();

  // ---- shifted-moment correction (own side), tid 0..3 = head ----
  if (tid < H_) {
    int h = tid;
    float del[E_];
#pragma unroll
    for (int e = 0; e < E_; e++) {
      float s = 0.f;
#pragma unroll
      for (int f = 0; f < F_; f++) s = fmaf(rawR[160+f], sw[SW_WIN + e*F_ + f], s);
      del[e] = s * invN;
    }
    float A[3], G[3];
#pragma unroll
    for (int d = 0; d < 3; d++) {
      float sq=0.f, sk=0.f, sv=0.f;
#pragma unroll
      for (int e = 0; e < E_; e++) {
        sq = fmaf(del[e], sw[SW_WQKVS + (h*3+d)*E_ + e], sq);
        sk = fmaf(del[e], sw[SW_WQKVS + (12 + h*3+d)*E_ + e], sk);
        sv = fmaf(del[e], sw[SW_WQKVS + (24 + h*3+d)*E_ + e], sv);
      }
      dq[h*3+d] = sq; A[d] = sk; G[d] = sv;
    }
    const float* R = &rawR[h*40];
    float S[39];
#pragma unroll
    for (int i = 0; i < 3; i++) S[i] = R[i] - Nf*A[i];
    const int PI[6] = {0,1,2,0,0,1}, PJ[6] = {0,1,2,1,2,2};
#pragma unroll
    for (int p = 0; p < 6; p++) {
      int i = PI[p], j = PJ[p];
      S[3+p] = R[3+p] - A[i]*R[j] - A[j]*R[i] + Nf*A[i]*A[j];
    }
#pragma unroll
    for (int cc = 0; cc < 3; cc++) S[9+cc] = R[9+cc] - Nf*G[cc];
#pragma unroll
    for (int i = 0; i < 3; i++)
#pragma unroll
      for (int cc = 0; cc < 3; cc++)
        S[12+i*3+cc] = R[12+i*3+cc] - A[i]*R[9+cc] - G[cc]*R[i] + Nf*A[i]*G[cc];
#pragma unroll
    for (int p = 0; p < 6; p++) {
      int i = PI[p], j = PJ[p];
#pragma unroll
      for (int cc = 0; cc < 3; cc++) {
        S[21+p*3+cc] = R[21+p*3+cc]
                     - A[i]*R[12+j*3+cc] - A[j]*R[12+i*3+cc]
                     - G[cc]*R[3+p]
                     + A[i]*A[j]*R[9+cc]
                     + A[i]*G[cc]*R[j] + A[j]*G[cc]*R[i]
                     - Nf*A[i]*A[j]*G[cc];
      }
    }
#pragma unroll
    for (int j = 0; j < 39; j++) smu[h*40+j] = S[j] * mom_scale(j);
    smu[h*40+39] = 0.f;
  }
  __syncthreads();

  // ================= Phase B =================
  if (!side) {                        // x: self-attn + cross-q (stays in registers)
#pragma unroll
    for (int tk = 0; tk < 4; tk++) {
      float attn[E_], i2[E_];
#pragma unroll
      for (int h = 0; h < H_; h++)
        attn_eval(&smu[h*40], (qq[tk][h*3+0]-dq[h*3+0])*SC, (qq[tk][h*3+1]-dq[h*3+1])*SC,
                  (qq[tk][h*3+2]-dq[h*3+2])*SC, &attn[h*3]);
#pragma unroll
      for (int e = 0; e < E_; e++) {
        float s = sw[SW_BOS + e];
#pragma unroll
        for (int j = 0; j < E_; j++) s = fmaf(attn[j], sw[SW_WOS + e*E_ + j], s);
        i2[e] = s;
      }
#pragma unroll
      for (int o = 0; o < 12; o++) {
        float s = sw[SW_BQKVC + o];
#pragma unroll
        for (int e = 0; e < E_; e++) s = fmaf(i2[e], sw[SW_WQKVC + o*E_ + e], s);
        qc[tk][o] = s;
      }
    }
  } else {                            // y: self-attn + cross k/v moments
#pragma unroll
    for (int p = 0; p < 2; p++) {
      float attn[E_], i2a[E_], i2b[E_];
#pragma unroll
      for (int h = 0; h < H_; h++)
        attn_eval(&smu[h*40], (qq[p*2][h*3+0]-dq[h*3+0])*SC, (qq[p*2][h*3+1]-dq[h*3+1])*SC,
                  (qq[p*2][h*3+2]-dq[h*3+2])*SC, &attn[h*3]);
#pragma unroll
      for (int e = 0; e < E_; e++) {
        float s = sw[SW_BOS + e];
#pragma unroll
        for (int j = 0; j < E_; j++) s = fmaf(attn[j], sw[SW_WOS + e*E_ + j], s);
        i2a[e] = s;
      }
#pragma unroll
      for (int h = 0; h < H_; h++)
        attn_eval(&smu[h*40], (qq[p*2+1][h*3+0]-dq[h*3+0])*SC, (qq[p*2+1][h*3+1]-dq[h*3+1])*SC,
                  (qq[p*2+1][h*3+2]-dq[h*3+2])*SC, &attn[h*3]);
#pragma unroll
      for (int e = 0; e < E_; e++) {
        float s = sw[SW_BOS + e];
#pragma unroll
        for (int j = 0; j < E_; j++) s = fmaf(attn[j], sw[SW_WOS + e*E_ + j], s);
        i2b[e] = s;
      }
#pragma unroll
      for (int h = 0; h < H_; h++) {
        float ka[6], kb[6];
#pragma unroll
        for (int d = 0; d < 6; d++) {
          int o = 12 + (d/3)*12 + h*3 + (d%3);
          float sa = sw[SW_BQKVC + o], sb = sa;
#pragma unroll
          for (int e = 0; e < E_; e++) {
            sa = fmaf(i2a[e], sw[SW_WQKVC + o*E_ + e], sa);
            sb = fmaf(i2b[e], sw[SW_WQKVC + o*E_ + e], sb);
          }
          ka[d] = sa; kb[d] = sb;
        }
        float m[40];
        mom_compute(ka[0], ka[1], ka[2], ka[3], ka[4], ka[5], m);
        mom_accum (kb[0], kb[1], kb[2], kb[3], kb[4], kb[5], m);
        m[39] = 0.f;
#pragma unroll
        for (int j = 0; j < 39; j++) {
          m[j] += __shfl_xor(m[j], 1);
          m[j] += __shfl_xor(m[j], 2);
        }
        if (rep) {
          if (p == 0) {
#pragma unroll
            for (int j4 = 0; j4 < 10; j4++)
              *(float4*)&red[qd*180 + h*40 + j4*4] =
                make_float4(m[j4*4], m[j4*4+1], m[j4*4+2], m[j4*4+3]);
          } else {
#pragma unroll
            for (int j = 0; j < 40; j++) red[qd*180 + h*40 + j] += m[j];
          }
        }
      }
    }
    __syncthreads();
    for (int col = tid; col < 160; col += 256) {
      float a = 0.f;
      for (int q = 0; q < 64; q++) a += red[q*180 + col];
      data_store(&psC[(size_t)b*160 + col], a);
    }
    if (tid >= 160 && tid < 163)
      data_store(&pYM[b*3 + (tid - 160)], rawR[160 + (tid - 160)]);
    __syncthreads();                  // drains vmcnt for all waves
    if (tid == 0) flag_set(&flags[b], TAG_C);
    return;                           // y block done
  }

  // ================= x: wait for y, load cross moments =================
  if (tid == 0) flag_wait(&flags[b], TAG_C);
  __syncthreads();
  if (tid < 160) {
    int j = tid - (tid/40)*40;
    smuC[tid] = data_load(&psC[(size_t)b*160 + tid]) * mom_scale(j);
  } else if (tid < 163) {
    myY[tid-160] = data_load(&pYM[b*3 + (tid-160)]) * invN;
  }
  __syncthreads();

  // ================= Phase C: cross-attn + Kabsch stats =================
  {
    float st[15];
#pragma unroll
    for (int i = 0; i < 15; i++) st[i] = 0.f;
#pragma unroll
    for (int tk = 0; tk < 4; tk++) {
      float attn[E_], c12[E_], co[3];
#pragma unroll
      for (int h = 0; h < H_; h++)
        attn_eval(&smuC[h*40], qc[tk][h*3+0]*SC, qc[tk][h*3+1]*SC, qc[tk][h*3+2]*SC, &attn[h*3]);
#pragma unroll
      for (int e = 0; e < E_; e++) {
        float s = sw[SW_BOC + e];
#pragma unroll
        for (int j = 0; j < E_; j++) s = fmaf(attn[j], sw[SW_WOC + e*E_ + j], s);
        c12[e] = s;
      }
#pragma unroll
      for (int k = 0; k < 3; k++) {
        float s = sw[SW_BOUT + k];
#pragma unroll
        for (int e = 0; e < E_; e++) s = fmaf(c12[e], sw[SW_WOUT + k*E_ + e], s);
        co[k] = s;
      }
      xr[tk][0] -= rawR[160]*invN; xr[tk][1] -= rawR[161]*invN; xr[tk][2] -= rawR[162]*invN;
      float A0 = co[0]+xr[tk][0], A1 = co[1]+xr[tk][1], A2 = co[2]+xr[tk][2];
      st[0]+=co[0]; st[1]+=co[1]; st[2]+=co[2];
      st[3]+=xr[tk][0]; st[4]+=xr[tk][1]; st[5]+=xr[tk][2];
      st[6]=fmaf(xr[tk][0],A0,st[6]);  st[7]=fmaf(xr[tk][0],A1,st[7]);  st[8]=fmaf(xr[tk][0],A2,st[8]);
      st[9]=fmaf(xr[tk][1],A0,st[9]);  st[10]=fmaf(xr[tk][1],A1,st[10]); st[11]=fmaf(xr[tk][1],A2,st[11]);
      st[12]=fmaf(xr[tk][2],A0,st[12]); st[13]=fmaf(xr[tk][2],A1,st[13]); st[14]=fmaf(xr[tk][2],A2,st[14]);
    }
#pragma unroll
    for (int i = 0; i < 15; i++) {
      st[i] += __shfl_down(st[i], 32); st[i] += __shfl_down(st[i], 16);
      st[i] += __shfl_down(st[i], 8);  st[i] += __shfl_down(st[i], 4);
      st[i] += __shfl_down(st[i], 2);  st[i] += __shfl_down(st[i], 1);
    }
    if ((tid & 63) == 0) {
      int wv = tid >> 6;
#pragma unroll
      for (int i = 0; i < 15; i++) sredK[wv][i] = st[i];
    }
  }
  __syncthreads();

  // ================= Phase D: polar (wave 0) + transform =================
  if (tid < 64) {
    float s[15];
#pragma unroll
    for (int i = 0; i < 15; i++) s[i] = sredK[0][i] + sredK[1][i] + sredK[2][i] + sredK[3][i];
    float cB[3] = { s[3]*invN, s[4]*invN, s[5]*invN };
    float cA[3] = { (s[0]+s[3])*invN, (s[1]+s[4])*invN, (s[2]+s[5])*invN };
    float X[9];
#pragma unroll
    for (int i = 0; i < 3; i++)
#pragma unroll
      for (int j = 0; j < 3; j++)
        X[i*3+j] = s[6 + i*3 + j] - Nf * cB[i] * cA[j];
    float fn = 0.f;
#pragma unroll
    for (int i = 0; i < 9; i++) fn += X[i]*X[i];
    float scl = rsqrtf(fn);
#pragma unroll
    for (int i = 0; i < 9; i++) X[i] *= scl;
    for (int it = 0; it < 24; it++) {
      float c00 =  X[4]*X[8]-X[5]*X[7];
      float c01 = -(X[3]*X[8]-X[5]*X[6]);
      float c02 =  X[3]*X[7]-X[4]*X[6];
      float c10 = -(X[1]*X[8]-X[2]*X[7]);
      float c11 =  X[0]*X[8]-X[2]*X[6];
      float c12_= -(X[0]*X[7]-X[1]*X[6]);
      float c20 =  X[1]*X[5]-X[2]*X[4];
      float c21 = -(X[0]*X[5]-X[2]*X[3]);
      float c22 =  X[0]*X[4]-X[1]*X[3];
      float det = X[0]*c00 + X[1]*c01 + X[2]*c02;
      float id = 0.5f / det;
      X[0]=0.5f*X[0]+c00*id; X[1]=0.5f*X[1]+c01*id; X[2]=0.5f*X[2]+c02*id;
      X[3]=0.5f*X[3]+c10*id; X[4]=0.5f*X[4]+c11*id; X[5]=0.5f*X[5]+c12_*id;
      X[6]=0.5f*X[6]+c20*id; X[7]=0.5f*X[7]+c21*id; X[8]=0.5f*X[8]+c22*id;
    }
    if (tid == 0) {
#pragma unroll
      for (int i = 0; i < 9; i++) sXf[i] = X[i];
#pragma unroll
      for (int k = 0; k < 3; k++)
        sXf[9+k] = cA[k] - (cB[0]*X[k] + cB[1]*X[3+k] + cB[2]*X[6+k]) + myY[k];
    }
  }
  __syncthreads();
  {
    float X0=sXf[0], X1=sXf[1], X2=sXf[2], X3=sXf[3], X4=sXf[4], X5=sXf[5],
          X6=sXf[6], X7=sXf[7], X8=sXf[8], t0=sXf[9], t1=sXf[10], t2=sXf[11];
#pragma unroll
    for (int tk = 0; tk < 4; tk++) {
      size_t t = (size_t)b * N_ + (tk>>1)*512 + (tk&1)*256 + tid;
      out[t*3+0] = fmaf(xr[tk][0], X0, fmaf(xr[tk][1], X3, fmaf(xr[tk][2], X6, t0)));
      out[t*3+1] = fmaf(xr[tk][0], X1, fmaf(xr[tk][1], X4, fmaf(xr[tk][2], X7, t1)));
      out[t*3+2] = fmaf(xr[tk][0], X2, fmaf(xr[tk][1], X5, fmaf(xr[tk][2], X8, t2)));
    }
  }
}

extern "C" void kernel_launch(void* const* d_in, const int* in_sizes, int n_in,
                              void* d_out, int out_size, void* d_ws, size_t ws_size,
                              hipStream_t stream) {
  const float* x_orig = (const float*)d_in[0];
  const float* y_orig = (const float*)d_in[1];
  const float* W_in   = (const float*)d_in[2];
  const float* b_in   = (const float*)d_in[3];
  const float* Wqkv_s = (const float*)d_in[4];
  const float* bqkv_s = (const float*)d_in[5];
  const float* Wo_s   = (const float*)d_in[6];
  const float* bo_s   = (const float*)d_in[7];
  const float* Wqkv_c = (const float*)d_in[8];
  const float* bqkv_c = (const float*)d_in[9];
  const float* Wo_c   = (const float*)d_in[10];
  const float* bo_c   = (const float*)d_in[11];
  const float* W_out  = (const float*)d_in[12];
  const float* b_out  = (const float*)d_in[13];
  float* ws = (float*)d_ws;

  k_all<<<32, 256, 0, stream>>>(x_orig, y_orig, W_in, b_in, Wqkv_s, bqkv_s,
                                Wo_s, bo_s, Wqkv_c, bqkv_c, Wo_c, bo_c,
                                W_out, b_out, ws, (float*)d_out);
}